// Round 4
// baseline (125.332 us; speedup 1.0000x reference)
//
#include <hip/hip_runtime.h>

#define NB 32
#define TLEN 480000
#define NF 1876                    // (480000 + 2*512 - 1024)/256 + 1
#define FR 4                       // frames per wave
#define WPR 469                    // ceil(NF/FR) waves per row
#define WTHREADS 256

// ---- DPP-based wave reduction: 4 VALU dpp-adds + 2 cross-row shuffles ----
template <int CTRL>
__device__ __forceinline__ float dpp_add(float x) {
    int y = __builtin_amdgcn_update_dpp(0, __float_as_int(x), CTRL, 0xF, 0xF, true);
    return x + __int_as_float(y);
}

__device__ __forceinline__ float wave_reduce(float s) {
    s = dpp_add<0xB1>(s);   // quad_perm(1,0,3,2) : xor1
    s = dpp_add<0x4E>(s);   // quad_perm(2,3,0,1) : xor2
    s = dpp_add<0x124>(s);  // row_ror:4
    s = dpp_add<0x128>(s);  // row_ror:8
    s += __shfl_xor(s, 16);
    s += __shfl_xor(s, 32);
    return s;
}

__device__ __forceinline__ float f4c(const float4& v, int j) {
    return j == 0 ? v.x : (j == 1 ? v.y : (j == 2 ? v.z : v.w));
}

// ---------------- kernel 1: per-frame windowed sums, max-MLP --------------
__global__ __launch_bounds__(WTHREADS, 4) void seg_frames(
    const float* __restrict__ est, const float* __restrict__ tgt,
    float* __restrict__ ws_part, float* __restrict__ ws_bs)
{
    const int tid  = threadIdx.x;
    const int lane = tid & 63;
    const int wave = tid >> 6;
    const int b    = blockIdx.y;
    const int wv   = blockIdx.x * 4 + wave;
    if (wv >= WPR) return;
    const int fb = wv * FR;

    const float* erow = est + (size_t)b * TLEN;
    const float* trow = tgt + (size_t)b * TLEN;

    float pe = 0.f, pt = 0.f;      // plain sums over owned samples (means)

    if (fb >= 4 && fb <= 1868) {
        // ================= fast path =================
        const float4* e4 = (const float4*)erow;
        const float4* t4 = (const float4*)trow;

        // issue ALL 14 loads up front — fully independent, max MLP
        float4 E[7], T[7];
#pragma unroll
        for (int m = 0; m < 7; ++m) {
            int g = 64 * (fb + m) - 128 + lane;
            E[m] = e4[g];
            T[m] = t4[g];
        }

        // w^2 at positions p = 256q + 4*lane + j  (hidden under load latency)
        float w2v[4][4];
#pragma unroll
        for (int q = 0; q < 4; ++q)
#pragma unroll
            for (int j = 0; j < 4; ++j) {
                float p = (float)(256 * q + 4 * lane + j);
                float w = 0.5f - 0.5f * cosf(6.28318530717958647692f * p * (1.0f / 1024.0f));
                w2v[q][j] = w * w;
            }

        // hop-major: rolling accumulators for 4 frames
        float acc[4][5];
#pragma unroll
        for (int i = 0; i < 4; ++i)
#pragma unroll
            for (int s5 = 0; s5 < 5; ++s5) acc[i][s5] = 0.f;

#pragma unroll
        for (int m = 0; m < 7; ++m) {
            float4 ev4 = E[m], tv4 = T[m];
#pragma unroll
            for (int j = 0; j < 4; ++j) {
                float e = f4c(ev4, j), t = f4c(tv4, j);
                float et = e * t, tt2 = t * t, ee2 = e * e;
#pragma unroll
                for (int i = 0; i < 4; ++i) {
                    if (m - i < 0 || m - i > 3) continue;   // const-folds
                    float w2 = w2v[m - i][j];
                    acc[i][0] = fmaf(w2, et,  acc[i][0]);
                    acc[i][1] = fmaf(w2, tt2, acc[i][1]);
                    acc[i][2] = fmaf(w2, ee2, acc[i][2]);
                    acc[i][3] = fmaf(w2, e,   acc[i][3]);
                    acc[i][4] = fmaf(w2, t,   acc[i][4]);
                }
            }
            if (m < 4) {           // owned samples [256fb-512, 256fb+511]
                pe += (ev4.x + ev4.y) + (ev4.z + ev4.w);
                pt += (tv4.x + tv4.y) + (tv4.z + tv4.w);
            }
        }

#pragma unroll
        for (int i = 0; i < 4; ++i) {
            float s0 = wave_reduce(acc[i][0]);
            float s1 = wave_reduce(acc[i][1]);
            float s2 = wave_reduce(acc[i][2]);
            float s3 = wave_reduce(acc[i][3]);
            float s4 = wave_reduce(acc[i][4]);
            if (lane == 0) {
                float* p = ws_part + (size_t)(b * NF + fb + i) * 5;
                p[0] = s0; p[1] = s1; p[2] = s2; p[3] = s3; p[4] = s4;
            }
        }
    } else {
        // ================= edge path (fb==0 or fb==1872) =================
        int nfr = NF - fb;
        if (nfr > FR) nfr = FR;

        float w2v[4][4];
#pragma unroll
        for (int q = 0; q < 4; ++q)
#pragma unroll
            for (int j = 0; j < 4; ++j) {
                float p = (float)(256 * q + 4 * lane + j);
                float w = 0.5f - 0.5f * cosf(6.28318530717958647692f * p * (1.0f / 1024.0f));
                w2v[q][j] = w * w;
            }

        for (int i = 0; i < nfr; ++i) {
            int f = fb + i;
            float s_et = 0.f, s_tt = 0.f, s_ee = 0.f, s_e = 0.f, s_t = 0.f;
#pragma unroll
            for (int q = 0; q < 4; ++q)
#pragma unroll
                for (int j = 0; j < 4; ++j) {
                    int s = 256 * f - 512 + 256 * q + 4 * lane + j;
                    int idx = s < 0 ? -s : (s >= TLEN ? 2 * (TLEN - 1) - s : s);
                    float ev = erow[idx], tv = trow[idx];
                    float w2 = w2v[q][j];
                    float et = ev * tv;
                    s_et = fmaf(w2, et,      s_et);
                    s_tt = fmaf(w2, tv * tv, s_tt);
                    s_ee = fmaf(w2, ev * ev, s_ee);
                    s_e  = fmaf(w2, ev, s_e);
                    s_t  = fmaf(w2, tv, s_t);
                }
            s_et = wave_reduce(s_et);
            s_tt = wave_reduce(s_tt);
            s_ee = wave_reduce(s_ee);
            s_e  = wave_reduce(s_e);
            s_t  = wave_reduce(s_t);
            if (lane == 0) {
                float* p = ws_part + (size_t)(b * NF + f) * 5;
                p[0] = s_et; p[1] = s_tt; p[2] = s_ee; p[3] = s_e; p[4] = s_t;
            }
        }

        // owned samples for the means (disjoint from fast waves' coverage)
        const float4* e4 = (const float4*)erow;
        const float4* t4 = (const float4*)trow;
        if (fb == 0) {
            // own [0, 512): 128 float4, 2 per lane
#pragma unroll
            for (int k = 0; k < 2; ++k) {
                float4 ev4 = e4[lane + 64 * k];
                float4 tv4 = t4[lane + 64 * k];
                pe += (ev4.x + ev4.y) + (ev4.z + ev4.w);
                pt += (tv4.x + tv4.y) + (tv4.z + tv4.w);
            }
        } else {
            // own [478720, 480000): 320 float4, 5 per lane
#pragma unroll
            for (int k = 0; k < 5; ++k) {
                int g = 119680 + lane + 64 * k;
                float4 ev4 = e4[g];
                float4 tv4 = t4[g];
                pe += (ev4.x + ev4.y) + (ev4.z + ev4.w);
                pt += (tv4.x + tv4.y) + (tv4.z + tv4.w);
            }
        }
    }

    // per-wave plain-sum partials -> workspace (for the row means)
    pe = wave_reduce(pe);
    pt = wave_reduce(pt);
    if (lane == 0) {
        ws_bs[(0 * NB + b) * WPR + wv] = pe;
        ws_bs[(1 * NB + b) * WPR + wv] = pt;
    }
}

// ---------------- kernel 2: reduce wave sums -> per-row means -------------
__global__ void seg_means(const float* __restrict__ ws_bs, float* __restrict__ ws_mean)
{
    int t = threadIdx.x;             // 256 threads, 1 block: 4 lanes per (sig,row)
    int pair = t >> 2, sub = t & 3;
    const float* p = ws_bs + pair * WPR;
    float s = 0.f;
    for (int c = sub; c < WPR; c += 4) s += p[c];
    s += __shfl_xor(s, 1);
    s += __shfl_xor(s, 2);
    if (sub == 0) ws_mean[pair] = s * (1.0f / (float)TLEN);
}

// ---------------- kernel 3: combine partials + means -> loss --------------
__global__ __launch_bounds__(WTHREADS) void seg_final(
    const float* __restrict__ ws_part, const float* __restrict__ ws_mean,
    float* __restrict__ out)
{
    int idx = blockIdx.x * WTHREADS + threadIdx.x;
    if (idx >= NB * NF) return;
    int b = idx / NF;
    const float* p = ws_part + (size_t)idx * 5;
    float me = ws_mean[b];
    float mt = ws_mean[NB + b];
    float S_et = p[0], S_tt = p[1], S_ee = p[2], S_e = p[3], S_t = p[4];
    const float W2 = 384.0f;         // sum of squared periodic Hann, exact

    float dot = S_et - mt * S_e - me * S_t + me * mt * W2;
    float tt  = S_tt - 2.0f * mt * S_t + mt * mt * W2;
    float ee  = S_ee - 2.0f * me * S_e + me * me * W2;

    float a     = dot / (tt + 1e-8f);
    float st2   = a * a * tt;
    float en2   = ee - 2.0f * a * dot + st2;
    float ratio = st2 / (en2 + 1e-8f);
    out[idx] = -10.0f * log10f(ratio + 1e-8f);
}

extern "C" void kernel_launch(void* const* d_in, const int* in_sizes, int n_in,
                              void* d_out, int out_size, void* d_ws, size_t ws_size,
                              hipStream_t stream)
{
    const float* est = (const float*)d_in[0];
    const float* tgt = (const float*)d_in[1];
    float* out = (float*)d_out;

    float* ws      = (float*)d_ws;
    float* ws_part = ws;                                   // NB*NF*5   floats
    float* ws_bs   = ws_part + (size_t)NB * NF * 5;        // 2*NB*WPR  floats
    float* ws_mean = ws_bs + 2 * NB * WPR;                 // 2*NB      floats

    dim3 grid1((WPR + 3) / 4, NB);
    seg_frames<<<grid1, WTHREADS, 0, stream>>>(est, tgt, ws_part, ws_bs);
    seg_means<<<1, WTHREADS, 0, stream>>>(ws_bs, ws_mean);
    dim3 grid3((NB * NF + WTHREADS - 1) / WTHREADS);
    seg_final<<<grid3, WTHREADS, 0, stream>>>(ws_part, ws_mean, out);
}

// Round 5
// 51.884 us; speedup vs baseline: 2.4156x; 2.4156x over previous
//
#include <hip/hip_runtime.h>

#define NB 32
#define TLEN 480000
#define NF 1876                    // (480000 + 2*512 - 1024)/256 + 1
#define FR 16                      // frames per wave
#define WPR 118                    // ceil(NF/FR) waves per row
#define WTHREADS 256

// ---- DPP-based wave reduction: 4 VALU dpp-adds + 2 cross-row shuffles ----
template <int CTRL>
__device__ __forceinline__ float dpp_add(float x) {
    int y = __builtin_amdgcn_update_dpp(0, __float_as_int(x), CTRL, 0xF, 0xF, true);
    return x + __int_as_float(y);
}

__device__ __forceinline__ float wave_reduce(float s) {
    s = dpp_add<0xB1>(s);   // quad_perm(1,0,3,2) : xor1
    s = dpp_add<0x4E>(s);   // quad_perm(2,3,0,1) : xor2
    s = dpp_add<0x124>(s);  // row_ror:4
    s = dpp_add<0x128>(s);  // row_ror:8  -> row-of-16 sums everywhere
    s += __shfl_xor(s, 16);
    s += __shfl_xor(s, 32);
    return s;
}

__device__ __forceinline__ float f4c(const float4& v, int j) {
    return j == 0 ? v.x : (j == 1 ? v.y : (j == 2 ? v.z : v.w));
}

// ------- kernel 1: per-frame windowed sums, 8-slot register pipeline ------
__global__ __launch_bounds__(WTHREADS) void seg_frames(
    const float* __restrict__ est, const float* __restrict__ tgt,
    float* __restrict__ ws_part, float* __restrict__ ws_bs)
{
    const int tid  = threadIdx.x;
    const int lane = tid & 63;
    const int wave = tid >> 6;
    const int b    = blockIdx.y;
    const int wv   = blockIdx.x * 4 + wave;
    if (wv >= WPR) return;
    const int fb = wv * FR;

    const float* erow = est + (size_t)b * TLEN;
    const float* trow = tgt + (size_t)b * TLEN;

    // w^2 at frame positions p = 256q + 4*lane + j  (reused 16x)
    float w2v[4][4];
#pragma unroll
    for (int q = 0; q < 4; ++q)
#pragma unroll
        for (int j = 0; j < 4; ++j) {
            float p = (float)(256 * q + 4 * lane + j);
            float w = 0.5f - 0.5f * cosf(6.28318530717958647692f * p * (1.0f / 1024.0f));
            w2v[q][j] = w * w;
        }

    float pe = 0.f, pt = 0.f;      // plain sums over owned hops (means)

    if (wv >= 1 && wv <= 116) {
        // ---------------- fast path: interior frames only ----------------
        const float4* e4 = (const float4*)erow;
        const float4* t4 = (const float4*)trow;
        const int gbase = 64 * fb - 128 + lane;

        // 8-slot rotating window; block m (m=0..18) lives in slot m&7
        float4 E[8], T[8];
#pragma unroll
        for (int m = 0; m < 8; ++m) {
            E[m] = e4[gbase + 64 * m];
            T[m] = t4[gbase + 64 * m];
        }

#pragma unroll
        for (int i = 0; i < FR; ++i) {
            float a0 = 0.f, a1 = 0.f, a2 = 0.f, a3 = 0.f, a4 = 0.f;
#pragma unroll
            for (int k = 0; k < 4; ++k) {
                float4 e = E[(i + k) & 7];
                float4 t = T[(i + k) & 7];
#pragma unroll
                for (int j = 0; j < 4; ++j) {
                    float ev = f4c(e, j), tv = f4c(t, j);
                    float w2 = w2v[k][j];
                    float we = w2 * ev, wt = w2 * tv;
                    a0 = fmaf(we, tv, a0);
                    a1 = fmaf(wt, tv, a1);
                    a2 = fmaf(we, ev, a2);
                    a3 += we;
                    a4 += wt;
                }
                if (k == 2) {      // k==2 block == hop fb+i (owned, disjoint)
                    pe += (e.x + e.y) + (e.z + e.w);
                    pt += (t.x + t.y) + (t.z + t.w);
                }
            }
            // prefetch block i+8 into the slot freed by frame i (~4.5-frame slack)
            if (i + 8 < 19) {
                E[i & 7] = e4[gbase + 64 * (i + 8)];
                T[i & 7] = t4[gbase + 64 * (i + 8)];
            }
            a0 = wave_reduce(a0);
            a1 = wave_reduce(a1);
            a2 = wave_reduce(a2);
            a3 = wave_reduce(a3);
            a4 = wave_reduce(a4);
            if (lane == 0) {
                float* p = ws_part + (size_t)(b * NF + fb + i) * 5;
                p[0] = a0; p[1] = a1; p[2] = a2; p[3] = a3; p[4] = a4;
            }
        }
    } else {
        // ---------------- edge path (wv==0 or wv==117) -------------------
        int nfr = NF - fb;
        if (nfr > FR) nfr = FR;
        for (int i = 0; i < nfr; ++i) {
            int f = fb + i;
            float a0 = 0.f, a1 = 0.f, a2 = 0.f, a3 = 0.f, a4 = 0.f;
#pragma unroll
            for (int q = 0; q < 4; ++q)
#pragma unroll
                for (int j = 0; j < 4; ++j) {
                    int s = 256 * f - 512 + 256 * q + 4 * lane + j;
                    int idx = s < 0 ? -s : (s >= TLEN ? 2 * (TLEN - 1) - s : s);
                    float ev = erow[idx], tv = trow[idx];
                    float w2 = w2v[q][j];
                    float we = w2 * ev, wt = w2 * tv;
                    a0 = fmaf(we, tv, a0);
                    a1 = fmaf(wt, tv, a1);
                    a2 = fmaf(we, ev, a2);
                    a3 += we;
                    a4 += wt;
                    if (q == 2 && f <= 1874) { pe += ev; pt += tv; }
                }
            a0 = wave_reduce(a0);
            a1 = wave_reduce(a1);
            a2 = wave_reduce(a2);
            a3 = wave_reduce(a3);
            a4 = wave_reduce(a4);
            if (lane == 0) {
                float* p = ws_part + (size_t)(b * NF + f) * 5;
                p[0] = a0; p[1] = a1; p[2] = a2; p[3] = a3; p[4] = a4;
            }
        }
    }

    // per-wave plain-sum partials -> workspace (for the row means)
    pe = wave_reduce(pe);
    pt = wave_reduce(pt);
    if (lane == 0) {
        ws_bs[(0 * NB + b) * WPR + wv] = pe;
        ws_bs[(1 * NB + b) * WPR + wv] = pt;
    }
}

// ---------------- kernel 2: reduce wave sums -> per-row means -------------
__global__ void seg_means(const float* __restrict__ ws_bs, float* __restrict__ ws_mean)
{
    int t = threadIdx.x;             // 256 threads, 1 block: 4 lanes per (sig,row)
    int pair = t >> 2, sub = t & 3;
    const float* p = ws_bs + pair * WPR;
    float s = 0.f;
    for (int c = sub; c < WPR; c += 4) s += p[c];
    s += __shfl_xor(s, 1);
    s += __shfl_xor(s, 2);
    if (sub == 0) ws_mean[pair] = s * (1.0f / (float)TLEN);
}

// ---------------- kernel 3: combine partials + means -> loss --------------
__global__ __launch_bounds__(WTHREADS) void seg_final(
    const float* __restrict__ ws_part, const float* __restrict__ ws_mean,
    float* __restrict__ out)
{
    int idx = blockIdx.x * WTHREADS + threadIdx.x;
    if (idx >= NB * NF) return;
    int b = idx / NF;
    const float* p = ws_part + (size_t)idx * 5;
    float me = ws_mean[b];
    float mt = ws_mean[NB + b];
    float S_et = p[0], S_tt = p[1], S_ee = p[2], S_e = p[3], S_t = p[4];
    const float W2 = 384.0f;         // sum of squared periodic Hann, exact

    float dot = S_et - mt * S_e - me * S_t + me * mt * W2;
    float tt  = S_tt - 2.0f * mt * S_t + mt * mt * W2;
    float ee  = S_ee - 2.0f * me * S_e + me * me * W2;

    float a     = dot / (tt + 1e-8f);
    float st2   = a * a * tt;
    float en2   = ee - 2.0f * a * dot + st2;
    float ratio = st2 / (en2 + 1e-8f);
    out[idx] = -10.0f * log10f(ratio + 1e-8f);
}

extern "C" void kernel_launch(void* const* d_in, const int* in_sizes, int n_in,
                              void* d_out, int out_size, void* d_ws, size_t ws_size,
                              hipStream_t stream)
{
    const float* est = (const float*)d_in[0];
    const float* tgt = (const float*)d_in[1];
    float* out = (float*)d_out;

    float* ws      = (float*)d_ws;
    float* ws_part = ws;                                   // NB*NF*5   floats
    float* ws_bs   = ws_part + (size_t)NB * NF * 5;        // 2*NB*WPR  floats
    float* ws_mean = ws_bs + 2 * NB * WPR;                 // 2*NB      floats

    dim3 grid1((WPR + 3) / 4, NB);
    seg_frames<<<grid1, WTHREADS, 0, stream>>>(est, tgt, ws_part, ws_bs);
    seg_means<<<1, WTHREADS, 0, stream>>>(ws_bs, ws_mean);
    dim3 grid3((NB * NF + WTHREADS - 1) / WTHREADS);
    seg_final<<<grid3, WTHREADS, 0, stream>>>(ws_part, ws_mean, out);
}